// Round 1
// baseline (1134.917 us; speedup 1.0000x reference)
//
#include <hip/hip_runtime.h>
#include <hip/hip_bf16.h>

#define N_NODES 50000
#define N_EDGES 640000
#define C 128            // IN_C == HID
#define TILE 16
#define EPB 256          // edges per block (16 tiles of 16)

typedef __bf16 bf16x8 __attribute__((ext_vector_type(8)));
typedef float  f32x4  __attribute__((ext_vector_type(4)));

// LDS tile: [16 rows][256 bf16] = 8KB. XOR swizzle (short-index units): flips
// bits 3..5 of the k-offset with row&7 -> ds_read_b128 across 16 rows at the
// same k hits 8 distinct bank groups instead of 1 (G4: 512B-stride conflict).
__device__ __forceinline__ int swz8(int row, int soff) {
    return row * 256 + (soff ^ ((row & 7) << 3));
}

// ---------------------------------------------------------------------------
// Kernel 1: edge messages + atomic scatter-sum into aggr (= d_out, pre-zeroed)
// C[m=channel][n=edge]; A = W_msg^T slice (registers), B = edge features (LDS)
// ---------------------------------------------------------------------------
__global__ __launch_bounds__(512) void edge_msg_kernel(
    const float* __restrict__ embed, const float* __restrict__ pos,
    const float* __restrict__ Wmsg,  const float* __restrict__ bmsg,
    const int*   __restrict__ eidx,  float* __restrict__ aggr)
{
    __shared__ short ldsF[16 * 256];
    __shared__ float sdist[16];
    __shared__ int   scol[16];

    const int t      = threadIdx.x;
    const int lane   = t & 63;
    const int wave   = t >> 6;        // 0..7 -> channel slice
    const int chbase = wave * 16;
    const int q      = lane >> 4;     // 0..3
    const int er     = lane & 15;     // A-row (channel) and B-col (edge)

    // A fragments: a[i] = A[m=lane&15][k=(lane>>4)*8+i] = W_msg[k][chbase+er]
    bf16x8 aW[8];
    {
        const int ch = chbase + er;
        #pragma unroll
        for (int ks = 0; ks < 8; ++ks) {
            #pragma unroll
            for (int i = 0; i < 8; ++i) {
                const int k = ks * 32 + q * 8 + i;
                aW[ks][i] = (__bf16)Wmsg[k * C + ch];
            }
        }
    }
    // epilogue per-lane channels: C row = q*4 + r
    float bm[4], w2[4];
    #pragma unroll
    for (int r = 0; r < 4; ++r) {
        const int ch = chbase + q * 4 + r;
        bm[r] = bmsg[ch];
        w2[r] = Wmsg[256 * C + ch];   // dist row of W_msg, kept in f32
    }

    const int e00 = blockIdx.x * EPB;
    for (int tile = 0; tile < EPB / TILE; ++tile) {
        const int e0 = e00 + tile * TILE;
        {   // stage 16 edges x 256 features (bf16) into LDS
            const int e = t >> 5, seg = t & 31;
            const int node = eidx[(seg < 16 ? 0 : N_EDGES) + e0 + e];
            const float* src = embed + (long)node * C + (seg & 15) * 8;
            const float4 f0 = *(const float4*)src;
            const float4 f1 = *(const float4*)(src + 4);
            bf16x8 v;
            v[0]=(__bf16)f0.x; v[1]=(__bf16)f0.y; v[2]=(__bf16)f0.z; v[3]=(__bf16)f0.w;
            v[4]=(__bf16)f1.x; v[5]=(__bf16)f1.y; v[6]=(__bf16)f1.z; v[7]=(__bf16)f1.w;
            *(bf16x8*)(&ldsF[swz8(e, seg * 8)]) = v;
            if (t < 16) {
                const int rIdx = eidx[e0 + t];
                const int cIdx = eidx[N_EDGES + e0 + t];
                const float dx = pos[rIdx*3+0] - pos[cIdx*3+0];
                const float dy = pos[rIdx*3+1] - pos[cIdx*3+1];
                const float dz = pos[rIdx*3+2] - pos[cIdx*3+2];
                sdist[t] = dx*dx + dy*dy + dz*dz;
                scol[t]  = cIdx;
            }
        }
        __syncthreads();

        f32x4 acc = {0.f, 0.f, 0.f, 0.f};
        #pragma unroll
        for (int ks = 0; ks < 8; ++ks) {
            const bf16x8 b = *(const bf16x8*)(&ldsF[swz8(er, ks * 32 + q * 8)]);
            acc = __builtin_amdgcn_mfma_f32_16x16x32_bf16(aW[ks], b, acc, 0, 0, 0);
        }

        const float d  = sdist[er];
        const int   cn = scol[er];
        float* dst = aggr + (long)cn * C + chbase + q * 4;
        #pragma unroll
        for (int r = 0; r < 4; ++r) {
            float m = acc[r] + bm[r] + d * w2[r];
            m = fmaxf(m, 0.f);
            atomicAdd(dst + r, m);
        }
        __syncthreads();   // LDS safe to overwrite next tile
    }
}

// ---------------------------------------------------------------------------
// Kernel 2: out = embed @ W_res + relu([embed, aggr] @ W_upd + b_upd)
// aggr lives in `out` on entry; overwritten in place (per-tile, single owner).
// ---------------------------------------------------------------------------
__global__ __launch_bounds__(512) void node_upd_kernel(
    const float* __restrict__ embed, const float* __restrict__ Wres,
    const float* __restrict__ Wupd,  const float* __restrict__ bupd,
    float* __restrict__ out)
{
    __shared__ short ldsF[16 * 256];

    const int t      = threadIdx.x;
    const int lane   = t & 63;
    const int wave   = t >> 6;
    const int chbase = wave * 16;
    const int q      = lane >> 4;
    const int nr     = lane & 15;

    bf16x8 aU[8], aR[4];
    {
        const int ch = chbase + nr;
        #pragma unroll
        for (int ks = 0; ks < 8; ++ks)
            #pragma unroll
            for (int i = 0; i < 8; ++i)
                aU[ks][i] = (__bf16)Wupd[(ks*32 + q*8 + i) * C + ch];
        #pragma unroll
        for (int ks = 0; ks < 4; ++ks)
            #pragma unroll
            for (int i = 0; i < 8; ++i)
                aR[ks][i] = (__bf16)Wres[(ks*32 + q*8 + i) * C + ch];
    }
    float bu[4];
    #pragma unroll
    for (int r = 0; r < 4; ++r) bu[r] = bupd[chbase + q*4 + r];

    const int ntiles = N_NODES / TILE;   // 3125
    for (int nt = blockIdx.x; nt < ntiles; nt += gridDim.x) {
        const int n0 = nt * TILE;
        {   // stage [embed | aggr] for 16 nodes
            const int nn = t >> 5, seg = t & 31;
            const float* base = (seg < 16) ? embed : out;
            const float* src  = base + (long)(n0 + nn) * C + (seg & 15) * 8;
            const float4 f0 = *(const float4*)src;
            const float4 f1 = *(const float4*)(src + 4);
            bf16x8 v;
            v[0]=(__bf16)f0.x; v[1]=(__bf16)f0.y; v[2]=(__bf16)f0.z; v[3]=(__bf16)f0.w;
            v[4]=(__bf16)f1.x; v[5]=(__bf16)f1.y; v[6]=(__bf16)f1.z; v[7]=(__bf16)f1.w;
            *(bf16x8*)(&ldsF[swz8(nn, seg * 8)]) = v;
        }
        __syncthreads();

        f32x4 au = {0.f,0.f,0.f,0.f}, ar = {0.f,0.f,0.f,0.f};
        #pragma unroll
        for (int ks = 0; ks < 8; ++ks) {
            const bf16x8 b = *(const bf16x8*)(&ldsF[swz8(nr, ks * 32 + q * 8)]);
            au = __builtin_amdgcn_mfma_f32_16x16x32_bf16(aU[ks], b, au, 0, 0, 0);
        }
        #pragma unroll
        for (int ks = 0; ks < 4; ++ks) {
            const bf16x8 b = *(const bf16x8*)(&ldsF[swz8(nr, ks * 32 + q * 8)]);
            ar = __builtin_amdgcn_mfma_f32_16x16x32_bf16(aR[ks], b, ar, 0, 0, 0);
        }
        __syncthreads();   // all LDS reads done before next tile's writes

        const int node = n0 + nr;
        float* dst = out + (long)node * C + chbase + q * 4;
        #pragma unroll
        for (int r = 0; r < 4; ++r)
            dst[r] = ar[r] + fmaxf(au[r] + bu[r], 0.f);
    }
}

extern "C" void kernel_launch(void* const* d_in, const int* in_sizes, int n_in,
                              void* d_out, int out_size, void* d_ws, size_t ws_size,
                              hipStream_t stream) {
    const float* embed = (const float*)d_in[0];
    const float* pos   = (const float*)d_in[1];
    const float* Wres  = (const float*)d_in[2];
    const float* Wmsg  = (const float*)d_in[3];
    const float* bmsg  = (const float*)d_in[4];
    const float* Wupd  = (const float*)d_in[5];
    const float* bupd  = (const float*)d_in[6];
    const int*   eidx  = (const int*)d_in[7];
    float* out = (float*)d_out;

    // d_out doubles as the aggregation buffer for kernel 1
    hipMemsetAsync(out, 0, (size_t)N_NODES * C * sizeof(float), stream);
    edge_msg_kernel<<<N_EDGES / EPB, 512, 0, stream>>>(embed, pos, Wmsg, bmsg, eidx, out);
    node_upd_kernel<<<625, 512, 0, stream>>>(embed, Wres, Wupd, bupd, out);
}

// Round 2
// 334.292 us; speedup vs baseline: 3.3950x; 3.3950x over previous
//
#include <hip/hip_runtime.h>
#include <hip/hip_bf16.h>

#define N_NODES 50000
#define N_EDGES 640000
#define C 128            // IN_C == HID
#define SCAN_CHUNK 1024
#define NCHUNK ((N_NODES + SCAN_CHUNK - 1) / SCAN_CHUNK)   // 49

typedef __bf16 bf16x8 __attribute__((ext_vector_type(8)));
typedef __bf16 bf16x4 __attribute__((ext_vector_type(4)));
typedef float  f32x4  __attribute__((ext_vector_type(4)));

// ---- d_ws layout (byte offsets, all 256-aligned) ----
#define WS_DEG      0           // N ints
#define WS_OFF      200192      // N+1 ints
#define WS_CURSOR   400896      // N ints
#define WS_CSUM     601088      // NCHUNK ints
#define WS_COFF     601344      // NCHUNK ints
#define WS_SRCS     601600      // E ints (edge src ids, sorted by dst)
#define WS_EMBEDB   3161600     // N*C bf16 (12.8 MB)
// total ≈ 15.97 MB

// swizzle for [16][128]-short LDS tile: XOR bits 3..5 of the short-offset
// with row&7 -> 16-lane frag reads hit 8 distinct 16B slots (2-way = free).
__device__ __forceinline__ int swzS(int row, int soff) {
    return row * 128 + (soff ^ ((row & 7) << 3));
}
// round-1 swizzle for [16][256]-short tile (node-update kernel)
__device__ __forceinline__ int swz8(int row, int soff) {
    return row * 256 + (soff ^ ((row & 7) << 3));
}

// ---------------------------------------------------------------------------
__global__ void cvt_kernel(const float* __restrict__ embed, __bf16* __restrict__ embedB) {
    const int i = blockIdx.x * 256 + threadIdx.x;     // one per 8 elems
    if (i >= N_NODES * C / 8) return;
    const float4 f0 = *(const float4*)(embed + (long)i * 8);
    const float4 f1 = *(const float4*)(embed + (long)i * 8 + 4);
    bf16x8 v;
    v[0]=(__bf16)f0.x; v[1]=(__bf16)f0.y; v[2]=(__bf16)f0.z; v[3]=(__bf16)f0.w;
    v[4]=(__bf16)f1.x; v[5]=(__bf16)f1.y; v[6]=(__bf16)f1.z; v[7]=(__bf16)f1.w;
    *(bf16x8*)(embedB + (long)i * 8) = v;
}

__global__ void hist_kernel(const int* __restrict__ eidx, int* __restrict__ deg) {
    const int e = blockIdx.x * 256 + threadIdx.x;
    if (e < N_EDGES) atomicAdd(&deg[eidx[N_EDGES + e]], 1);
}

__global__ void chunksum_kernel(const int* __restrict__ deg, int* __restrict__ csum) {
    __shared__ int lds[SCAN_CHUNK];
    const int t = threadIdx.x, g = blockIdx.x * SCAN_CHUNK + t;
    lds[t] = (g < N_NODES) ? deg[g] : 0;
    __syncthreads();
    for (int s = SCAN_CHUNK / 2; s > 0; s >>= 1) {
        if (t < s) lds[t] += lds[t + s];
        __syncthreads();
    }
    if (t == 0) csum[blockIdx.x] = lds[0];
}

__global__ void chunkoff_kernel(const int* __restrict__ csum, int* __restrict__ coff,
                                int* __restrict__ off) {
    if (threadIdx.x == 0) {
        int run = 0;
        for (int i = 0; i < NCHUNK; ++i) { coff[i] = run; run += csum[i]; }
        off[N_NODES] = run;   // == E
    }
}

__global__ void scan_kernel(const int* __restrict__ deg, const int* __restrict__ coff,
                            int* __restrict__ off, int* __restrict__ cursor) {
    __shared__ int lds[SCAN_CHUNK];
    const int t = threadIdx.x, g = blockIdx.x * SCAN_CHUNK + t;
    const int x = (g < N_NODES) ? deg[g] : 0;
    lds[t] = x;
    __syncthreads();
    for (int s = 1; s < SCAN_CHUNK; s <<= 1) {       // Hillis-Steele inclusive
        const int v = (t >= s) ? lds[t - s] : 0;
        __syncthreads();
        lds[t] += v;
        __syncthreads();
    }
    const int excl = lds[t] - x + coff[blockIdx.x];
    if (g < N_NODES) { off[g] = excl; cursor[g] = excl; }
}

__global__ void scatter_kernel(const int* __restrict__ eidx, int* __restrict__ cursor,
                               int* __restrict__ srcS) {
    const int e = blockIdx.x * 256 + threadIdx.x;
    if (e < N_EDGES) {
        const int r = eidx[e], c = eidx[N_EDGES + e];
        const int p = atomicAdd(&cursor[c], 1);
        srcS[p] = r;
    }
}

// ---------------------------------------------------------------------------
// Aggregate: per node n, aggr[n] = sum over incoming edges of
//   relu(W_msg^T · cat(src, dst=n, dist) + b).  CSR order, no atomics.
// MFMA C[m=edge][n=ch]: A = edge/dst features (LDS), B = W_msg slice (regs).
// D layout: col=lane&15 -> ch, row=(lane>>4)*4+r -> edge. Edge-reduction =
// 3 register adds + 2 shfl_xor. 8 waves cover 128 channels.
// ---------------------------------------------------------------------------
__global__ __launch_bounds__(512) void aggr_kernel(
    const __bf16* __restrict__ embedB, const float* __restrict__ pos,
    const float* __restrict__ Wmsg,    const float* __restrict__ bmsg,
    const int*   __restrict__ off,     const int*   __restrict__ srcS,
    float* __restrict__ out)
{
    __shared__ short ldsS[16 * 128];   // 16 src rows x 128 feats (bf16)
    __shared__ short ldsD[128];        // dst feats (bf16)
    __shared__ float sdist[16];

    const int t = threadIdx.x, lane = t & 63, wave = t >> 6;
    const int chbase = wave * 16, q = lane >> 4, er = lane & 15;
    const int ch = chbase + er;

    // B fragments: b[i] = W_msg[k=(lane>>4)*8+i + ks*32][col=ch]
    bf16x8 wB[8];
    #pragma unroll
    for (int ks = 0; ks < 8; ++ks)
        #pragma unroll
        for (int i = 0; i < 8; ++i)
            wB[ks][i] = (__bf16)Wmsg[(ks * 32 + q * 8 + i) * C + ch];
    const float bmv = bmsg[ch];
    const float w2v = Wmsg[256 * C + ch];   // dist row, kept in f32

    for (int n = blockIdx.x; n < N_NODES; n += gridDim.x) {
        const int o0 = off[n], o1 = off[n + 1];
        // stage dst features (uniform across A-rows -> plain layout, broadcast reads)
        if (t < 16)
            *(bf16x8*)(&ldsD[t * 8]) = *(const bf16x8*)(embedB + (long)n * C + t * 8);
        float px = 0.f, py = 0.f, pz = 0.f;
        if (t < 16) { px = pos[n * 3]; py = pos[n * 3 + 1]; pz = pos[n * 3 + 2]; }

        float acc = 0.f;
        for (int t0 = o0; t0 < o1; t0 += 16) {
            const int rem = min(16, o1 - t0);
            {   // stage up to 16 src rows (32 threads/row, 8B each)
                const int e = t >> 5, seg = t & 31;
                if (e < rem) {
                    const int s = srcS[t0 + e];
                    *(bf16x4*)(&ldsS[swzS(e, seg * 4)]) =
                        *(const bf16x4*)(embedB + (long)s * C + seg * 4);
                }
            }
            if (t < 16) {
                float d = 0.f;
                if (t < rem) {
                    const int s = srcS[t0 + t];
                    const float dx = pos[s*3] - px, dy = pos[s*3+1] - py, dz = pos[s*3+2] - pz;
                    d = dx*dx + dy*dy + dz*dz;
                }
                sdist[t] = d;
            }
            __syncthreads();

            f32x4 mac = {0.f, 0.f, 0.f, 0.f};
            #pragma unroll
            for (int ks = 0; ks < 4; ++ks) {        // src half (K 0..127)
                const bf16x8 a = *(const bf16x8*)(&ldsS[swzS(er, ks * 32 + q * 8)]);
                mac = __builtin_amdgcn_mfma_f32_16x16x32_bf16(a, wB[ks], mac, 0, 0, 0);
            }
            #pragma unroll
            for (int ks = 4; ks < 8; ++ks) {        // dst half (K 128..255), uniform rows
                const bf16x8 a = *(const bf16x8*)(&ldsD[(ks - 4) * 32 + q * 8]);
                mac = __builtin_amdgcn_mfma_f32_16x16x32_bf16(a, wB[ks], mac, 0, 0, 0);
            }

            float part = 0.f;
            #pragma unroll
            for (int r = 0; r < 4; ++r) {
                const int row = q * 4 + r;          // edge index within tile
                float v = mac[r] + bmv + sdist[row] * w2v;
                v = fmaxf(v, 0.f);
                part += (row < rem) ? v : 0.f;
            }
            part += __shfl_xor(part, 16);
            part += __shfl_xor(part, 32);
            acc += part;
            __syncthreads();                        // LDS reuse next tile/node
        }
        if (lane < 16) out[(long)n * C + ch] = acc; // q==0 lanes, 64B/wave coalesced
    }
}

// ---------------------------------------------------------------------------
// Node update: out = embed @ W_res + relu([embed, aggr] @ W_upd + b_upd)
// (aggr lives in `out` on entry; overwritten in place, single-owner tiles)
// ---------------------------------------------------------------------------
__global__ __launch_bounds__(512) void node_upd_kernel(
    const __bf16* __restrict__ embedB, const float* __restrict__ Wres,
    const float*  __restrict__ Wupd,   const float* __restrict__ bupd,
    float* __restrict__ out)
{
    __shared__ short ldsF[16 * 256];

    const int t = threadIdx.x, lane = t & 63, wave = t >> 6;
    const int chbase = wave * 16, q = lane >> 4, nr = lane & 15;

    bf16x8 aU[8], aR[4];
    {
        const int ch = chbase + nr;
        #pragma unroll
        for (int ks = 0; ks < 8; ++ks)
            #pragma unroll
            for (int i = 0; i < 8; ++i)
                aU[ks][i] = (__bf16)Wupd[(ks*32 + q*8 + i) * C + ch];
        #pragma unroll
        for (int ks = 0; ks < 4; ++ks)
            #pragma unroll
            for (int i = 0; i < 8; ++i)
                aR[ks][i] = (__bf16)Wres[(ks*32 + q*8 + i) * C + ch];
    }
    float bu[4];
    #pragma unroll
    for (int r = 0; r < 4; ++r) bu[r] = bupd[chbase + q*4 + r];

    const int ntiles = N_NODES / 16;   // 3125
    for (int nt = blockIdx.x; nt < ntiles; nt += gridDim.x) {
        const int n0 = nt * 16;
        {   // stage [embed(bf16 copy) | aggr(f32 in out)] for 16 nodes
            const int nn = t >> 5, seg = t & 31;
            bf16x8 v;
            if (seg < 16) {
                v = *(const bf16x8*)(embedB + (long)(n0 + nn) * C + (seg & 15) * 8);
            } else {
                const float* src = out + (long)(n0 + nn) * C + (seg & 15) * 8;
                const float4 f0 = *(const float4*)src;
                const float4 f1 = *(const float4*)(src + 4);
                v[0]=(__bf16)f0.x; v[1]=(__bf16)f0.y; v[2]=(__bf16)f0.z; v[3]=(__bf16)f0.w;
                v[4]=(__bf16)f1.x; v[5]=(__bf16)f1.y; v[6]=(__bf16)f1.z; v[7]=(__bf16)f1.w;
            }
            *(bf16x8*)(&ldsF[swz8(nn, seg * 8)]) = v;
        }
        __syncthreads();

        f32x4 au = {0.f,0.f,0.f,0.f}, ar = {0.f,0.f,0.f,0.f};
        #pragma unroll
        for (int ks = 0; ks < 8; ++ks) {
            const bf16x8 b = *(const bf16x8*)(&ldsF[swz8(nr, ks * 32 + q * 8)]);
            au = __builtin_amdgcn_mfma_f32_16x16x32_bf16(aU[ks], b, au, 0, 0, 0);
        }
        #pragma unroll
        for (int ks = 0; ks < 4; ++ks) {
            const bf16x8 b = *(const bf16x8*)(&ldsF[swz8(nr, ks * 32 + q * 8)]);
            ar = __builtin_amdgcn_mfma_f32_16x16x32_bf16(aR[ks], b, ar, 0, 0, 0);
        }
        __syncthreads();

        const int node = n0 + nr;
        float* dst = out + (long)node * C + chbase + q * 4;
        #pragma unroll
        for (int r = 0; r < 4; ++r)
            dst[r] = ar[r] + fmaxf(au[r] + bu[r], 0.f);
    }
}

extern "C" void kernel_launch(void* const* d_in, const int* in_sizes, int n_in,
                              void* d_out, int out_size, void* d_ws, size_t ws_size,
                              hipStream_t stream) {
    const float* embed = (const float*)d_in[0];
    const float* pos   = (const float*)d_in[1];
    const float* Wres  = (const float*)d_in[2];
    const float* Wmsg  = (const float*)d_in[3];
    const float* bmsg  = (const float*)d_in[4];
    const float* Wupd  = (const float*)d_in[5];
    const float* bupd  = (const float*)d_in[6];
    const int*   eidx  = (const int*)d_in[7];
    float* out = (float*)d_out;

    char* ws = (char*)d_ws;
    int*    deg    = (int*)(ws + WS_DEG);
    int*    off    = (int*)(ws + WS_OFF);
    int*    cursor = (int*)(ws + WS_CURSOR);
    int*    csum   = (int*)(ws + WS_CSUM);
    int*    coff   = (int*)(ws + WS_COFF);
    int*    srcS   = (int*)(ws + WS_SRCS);
    __bf16* embedB = (__bf16*)(ws + WS_EMBEDB);

    hipMemsetAsync(deg, 0, N_NODES * sizeof(int), stream);
    cvt_kernel<<<N_NODES * C / 8 / 256, 256, 0, stream>>>(embed, embedB);
    hist_kernel<<<N_EDGES / 256, 256, 0, stream>>>(eidx, deg);
    chunksum_kernel<<<NCHUNK, SCAN_CHUNK, 0, stream>>>(deg, csum);
    chunkoff_kernel<<<1, 64, 0, stream>>>(csum, coff, off);
    scan_kernel<<<NCHUNK, SCAN_CHUNK, 0, stream>>>(deg, coff, off, cursor);
    scatter_kernel<<<N_EDGES / 256, 256, 0, stream>>>(eidx, cursor, srcS);
    aggr_kernel<<<2048, 512, 0, stream>>>(embedB, pos, Wmsg, bmsg, off, srcS, out);
    node_upd_kernel<<<625, 512, 0, stream>>>(embedB, Wres, Wupd, bupd, out);
}

// Round 3
// 171.841 us; speedup vs baseline: 6.6045x; 1.9454x over previous
//
#include <hip/hip_runtime.h>
#include <hip/hip_bf16.h>

#define N_NODES 50000
#define N_EDGES 640000
#define C 128            // IN_C == HID
#define SCAN_CHUNK 1024
#define NCHUNK ((N_NODES + SCAN_CHUNK - 1) / SCAN_CHUNK)   // 49
#define NTILES (N_NODES / 16)                               // 3125

typedef __bf16 bf16x8 __attribute__((ext_vector_type(8)));
typedef __bf16 bf16x4 __attribute__((ext_vector_type(4)));
typedef float  f32x4  __attribute__((ext_vector_type(4)));

// ---- d_ws layout (byte offsets). deg doubles as the scatter cursor. ----
#define WS_DEG      0           // N ints (histogram, then cursor)
#define WS_OFF      200192      // N+1 ints (CSR row offsets)
#define WS_CSUM     400640      // NCHUNK ints
#define WS_COFF     400896      // NCHUNK ints
#define WS_SRCS     401152      // E ints (src ids sorted by dst)
#define WS_HSRC     2961152     // N*C bf16 = 12.8 MB
// total 15,761,152 B (≤ round-2's proven 15.97 MB)

// XOR-swizzle for [16][128]-short LDS tiles: flip short-offset bits 3..5 with
// row&7 -> frag reads across 16 rows hit 8 distinct 16B slots (2-way = free).
__device__ __forceinline__ int swzS(int row, int soff) {
    return row * 128 + (soff ^ ((row & 7) << 3));
}
// [16][256]-short variant (node-update staging)
__device__ __forceinline__ int swz8(int row, int soff) {
    return row * 256 + (soff ^ ((row & 7) << 3));
}

// ---------------------------------------------------------------------------
// CSR build chain
// ---------------------------------------------------------------------------
__global__ void hist_kernel(const int* __restrict__ eidx, int* __restrict__ deg) {
    const int e = blockIdx.x * 256 + threadIdx.x;
    if (e < N_EDGES) atomicAdd(&deg[eidx[N_EDGES + e]], 1);
}

__global__ void chunksum_kernel(const int* __restrict__ deg, int* __restrict__ csum) {
    __shared__ int lds[SCAN_CHUNK];
    const int t = threadIdx.x, g = blockIdx.x * SCAN_CHUNK + t;
    lds[t] = (g < N_NODES) ? deg[g] : 0;
    __syncthreads();
    for (int s = SCAN_CHUNK / 2; s > 0; s >>= 1) {
        if (t < s) lds[t] += lds[t + s];
        __syncthreads();
    }
    if (t == 0) csum[blockIdx.x] = lds[0];
}

__global__ void chunkoff_kernel(const int* __restrict__ csum, int* __restrict__ coff,
                                int* __restrict__ off) {
    if (threadIdx.x == 0) {
        int run = 0;
        for (int i = 0; i < NCHUNK; ++i) { coff[i] = run; run += csum[i]; }
        off[N_NODES] = run;   // == E
    }
}

// writes off[] and resets deg[] to the exclusive prefix (scatter cursor)
__global__ void scan_kernel(const int* __restrict__ coff, int* __restrict__ deg,
                            int* __restrict__ off) {
    __shared__ int lds[SCAN_CHUNK];
    const int t = threadIdx.x, g = blockIdx.x * SCAN_CHUNK + t;
    const int x = (g < N_NODES) ? deg[g] : 0;
    lds[t] = x;
    __syncthreads();
    for (int s = 1; s < SCAN_CHUNK; s <<= 1) {       // Hillis-Steele inclusive
        const int v = (t >= s) ? lds[t - s] : 0;
        __syncthreads();
        lds[t] += v;
        __syncthreads();
    }
    const int excl = lds[t] - x + coff[blockIdx.x];
    if (g < N_NODES) { off[g] = excl; deg[g] = excl; }
}

__global__ void scatter_kernel(const int* __restrict__ eidx, int* __restrict__ cursor,
                               int* __restrict__ srcS) {
    const int e = blockIdx.x * 256 + threadIdx.x;
    if (e < N_EDGES) {
        const int r = eidx[e], c = eidx[N_EDGES + e];
        const int p = atomicAdd(&cursor[c], 1);
        srcS[p] = r;
    }
}

// ---------------------------------------------------------------------------
// Precompute Hsrc = embed @ Wmsg[0:128]          (bf16, ws)
//            Hdst = embed @ Wmsg[128:256] + b    (f32, -> d_out)
// Same wave->16ch decomposition as node_upd; weights in registers.
// ---------------------------------------------------------------------------
__global__ __launch_bounds__(512) void precomp_kernel(
    const float* __restrict__ embed, const float* __restrict__ Wmsg,
    const float* __restrict__ bmsg,  __bf16* __restrict__ Hsrc,
    float* __restrict__ Hdst)
{
    __shared__ short lds[16 * 128];

    const int t = threadIdx.x, lane = t & 63, wave = t >> 6;
    const int chbase = wave * 16, q = lane >> 4, nr = lane & 15;
    const int ch = chbase + nr;

    bf16x8 aS[4], aD[4];
    #pragma unroll
    for (int ks = 0; ks < 4; ++ks)
        #pragma unroll
        for (int i = 0; i < 8; ++i) {
            const int k = ks * 32 + q * 8 + i;
            aS[ks][i] = (__bf16)Wmsg[k * C + ch];
            aD[ks][i] = (__bf16)Wmsg[(128 + k) * C + ch];
        }
    float bias[4];
    #pragma unroll
    for (int r = 0; r < 4; ++r) bias[r] = bmsg[chbase + q * 4 + r];

    for (int nt = blockIdx.x; nt < NTILES; nt += gridDim.x) {
        const int n0 = nt * 16;
        {   // stage 16 nodes x 128 feats: f32 -> bf16 LDS
            const int row = t >> 5, seg = t & 31;
            const float4 f = *(const float4*)(embed + (long)(n0 + row) * C + seg * 4);
            bf16x4 v;
            v[0]=(__bf16)f.x; v[1]=(__bf16)f.y; v[2]=(__bf16)f.z; v[3]=(__bf16)f.w;
            *(bf16x4*)(&lds[swzS(row, seg * 4)]) = v;
        }
        __syncthreads();

        f32x4 hs = {0.f,0.f,0.f,0.f}, hd = {0.f,0.f,0.f,0.f};
        #pragma unroll
        for (int ks = 0; ks < 4; ++ks) {
            const bf16x8 b = *(const bf16x8*)(&lds[swzS(nr, ks * 32 + q * 8)]);
            hs = __builtin_amdgcn_mfma_f32_16x16x32_bf16(aS[ks], b, hs, 0, 0, 0);
            hd = __builtin_amdgcn_mfma_f32_16x16x32_bf16(aD[ks], b, hd, 0, 0, 0);
        }
        __syncthreads();

        // D: col(lane&15)=node, row(q*4+r)=ch
        const int node = n0 + nr;
        bf16x4 vs;
        f32x4  vd;
        #pragma unroll
        for (int r = 0; r < 4; ++r) { vs[r] = (__bf16)hs[r]; vd[r] = hd[r] + bias[r]; }
        *(bf16x4*)(Hsrc + (long)node * C + chbase + q * 4) = vs;
        *(f32x4*)(Hdst + (long)node * C + chbase + q * 4) = vd;
    }
}

// ---------------------------------------------------------------------------
// Aggregate: one node per WAVE, no LDS, no barriers, no atomics.
// aggr[n][ch] = sum_e relu(Hsrc[src_e][ch] + Hdst[n][ch] + dist_e * w2[ch])
// Hdst lives in `out` on entry; replaced by aggr (single-owner wave).
// Lane owns channels {2*lane, 2*lane+1}; CSR loop is wave-uniform (scalarized).
// ---------------------------------------------------------------------------
__global__ __launch_bounds__(256) void aggr_kernel(
    const __bf16* __restrict__ Hsrc, const float* __restrict__ pos,
    const float*  __restrict__ Wmsg, const int* __restrict__ off,
    const int*    __restrict__ srcS, float* __restrict__ out)
{
    const int lane = threadIdx.x & 63;
    const int wv   = __builtin_amdgcn_readfirstlane(threadIdx.x >> 6);
    const int gw   = blockIdx.x * 4 + wv;
    const int nw   = gridDim.x * 4;
    const int c2   = lane * 2;

    const float w2a = Wmsg[256 * C + c2];
    const float w2b = Wmsg[256 * C + c2 + 1];

    for (int n = gw; n < N_NODES; n += nw) {
        const int o0 = off[n], o1 = off[n + 1];
        const float2 hd = *(const float2*)(out + (long)n * C + c2);
        const float px = pos[n * 3], py = pos[n * 3 + 1], pz = pos[n * 3 + 2];
        float a0 = 0.f, a1 = 0.f;
        for (int e = o0; e < o1; ++e) {
            const int s = srcS[e];                               // s_load
            const float dx = pos[s * 3]     - px;                // s_loads
            const float dy = pos[s * 3 + 1] - py;
            const float dz = pos[s * 3 + 2] - pz;
            const float d  = dx * dx + dy * dy + dz * dz;
            const unsigned hsb = *(const unsigned*)(Hsrc + (long)s * C + c2);
            const float f0 = __uint_as_float(hsb << 16);         // bf16 lo -> f32
            const float f1 = __uint_as_float(hsb & 0xffff0000u); // bf16 hi -> f32
            a0 += fmaxf(f0 + hd.x + d * w2a, 0.f);
            a1 += fmaxf(f1 + hd.y + d * w2b, 0.f);
        }
        *(float2*)(out + (long)n * C + c2) = make_float2(a0, a1);
    }
}

// ---------------------------------------------------------------------------
// Node update: out = embed @ W_res + relu([embed, aggr] @ W_upd + b_upd)
// (aggr lives in `out` on entry; overwritten in place, single-owner tiles)
// ---------------------------------------------------------------------------
__global__ __launch_bounds__(512) void node_upd_kernel(
    const float* __restrict__ embed, const float* __restrict__ Wres,
    const float* __restrict__ Wupd,  const float* __restrict__ bupd,
    float* __restrict__ out)
{
    __shared__ short ldsF[16 * 256];

    const int t = threadIdx.x, lane = t & 63, wave = t >> 6;
    const int chbase = wave * 16, q = lane >> 4, nr = lane & 15;

    bf16x8 aU[8], aR[4];
    {
        const int ch = chbase + nr;
        #pragma unroll
        for (int ks = 0; ks < 8; ++ks)
            #pragma unroll
            for (int i = 0; i < 8; ++i)
                aU[ks][i] = (__bf16)Wupd[(ks*32 + q*8 + i) * C + ch];
        #pragma unroll
        for (int ks = 0; ks < 4; ++ks)
            #pragma unroll
            for (int i = 0; i < 8; ++i)
                aR[ks][i] = (__bf16)Wres[(ks*32 + q*8 + i) * C + ch];
    }
    float bu[4];
    #pragma unroll
    for (int r = 0; r < 4; ++r) bu[r] = bupd[chbase + q*4 + r];

    for (int nt = blockIdx.x; nt < NTILES; nt += gridDim.x) {
        const int n0 = nt * 16;
        {   // stage [embed(f32->bf16) | aggr(f32 in out)] for 16 nodes
            const int nn = t >> 5, seg = t & 31;
            const float* base = (seg < 16) ? embed : out;
            const float* src  = base + (long)(n0 + nn) * C + (seg & 15) * 8;
            const float4 f0 = *(const float4*)src;
            const float4 f1 = *(const float4*)(src + 4);
            bf16x8 v;
            v[0]=(__bf16)f0.x; v[1]=(__bf16)f0.y; v[2]=(__bf16)f0.z; v[3]=(__bf16)f0.w;
            v[4]=(__bf16)f1.x; v[5]=(__bf16)f1.y; v[6]=(__bf16)f1.z; v[7]=(__bf16)f1.w;
            *(bf16x8*)(&ldsF[swz8(nn, seg * 8)]) = v;
        }
        __syncthreads();

        f32x4 au = {0.f,0.f,0.f,0.f}, ar = {0.f,0.f,0.f,0.f};
        #pragma unroll
        for (int ks = 0; ks < 8; ++ks) {
            const bf16x8 b = *(const bf16x8*)(&ldsF[swz8(nr, ks * 32 + q * 8)]);
            au = __builtin_amdgcn_mfma_f32_16x16x32_bf16(aU[ks], b, au, 0, 0, 0);
        }
        #pragma unroll
        for (int ks = 0; ks < 4; ++ks) {
            const bf16x8 b = *(const bf16x8*)(&ldsF[swz8(nr, ks * 32 + q * 8)]);
            ar = __builtin_amdgcn_mfma_f32_16x16x32_bf16(aR[ks], b, ar, 0, 0, 0);
        }
        __syncthreads();

        const int node = n0 + nr;
        float* dst = out + (long)node * C + chbase + q * 4;
        #pragma unroll
        for (int r = 0; r < 4; ++r)
            dst[r] = ar[r] + fmaxf(au[r] + bu[r], 0.f);
    }
}

extern "C" void kernel_launch(void* const* d_in, const int* in_sizes, int n_in,
                              void* d_out, int out_size, void* d_ws, size_t ws_size,
                              hipStream_t stream) {
    const float* embed = (const float*)d_in[0];
    const float* pos   = (const float*)d_in[1];
    const float* Wres  = (const float*)d_in[2];
    const float* Wmsg  = (const float*)d_in[3];
    const float* bmsg  = (const float*)d_in[4];
    const float* Wupd  = (const float*)d_in[5];
    const float* bupd  = (const float*)d_in[6];
    const int*   eidx  = (const int*)d_in[7];
    float* out = (float*)d_out;

    char* ws = (char*)d_ws;
    int*    deg  = (int*)(ws + WS_DEG);     // histogram -> cursor
    int*    off  = (int*)(ws + WS_OFF);
    int*    csum = (int*)(ws + WS_CSUM);
    int*    coff = (int*)(ws + WS_COFF);
    int*    srcS = (int*)(ws + WS_SRCS);
    __bf16* Hsrc = (__bf16*)(ws + WS_HSRC);

    hipMemsetAsync(deg, 0, N_NODES * sizeof(int), stream);
    precomp_kernel<<<1024, 512, 0, stream>>>(embed, Wmsg, bmsg, Hsrc, out);
    hist_kernel<<<N_EDGES / 256, 256, 0, stream>>>(eidx, deg);
    chunksum_kernel<<<NCHUNK, SCAN_CHUNK, 0, stream>>>(deg, csum);
    chunkoff_kernel<<<1, 64, 0, stream>>>(csum, coff, off);
    scan_kernel<<<NCHUNK, SCAN_CHUNK, 0, stream>>>(coff, deg, off);
    scatter_kernel<<<N_EDGES / 256, 256, 0, stream>>>(eidx, deg, srcS);
    aggr_kernel<<<4096, 256, 0, stream>>>(Hsrc, pos, Wmsg, off, srcS, out);
    node_upd_kernel<<<1024, 512, 0, stream>>>(embed, Wres, Wupd, bupd, out);
}

// Round 4
// 152.867 us; speedup vs baseline: 7.4242x; 1.1241x over previous
//
#include <hip/hip_runtime.h>
#include <hip/hip_bf16.h>

#define N_NODES 50000
#define N_EDGES 640000
#define C 128            // IN_C == HID
#define SCAN_CHUNK 1024
#define NCHUNK ((N_NODES + SCAN_CHUNK - 1) / SCAN_CHUNK)   // 49
#define NTILES (N_NODES / 16)                               // 3125

typedef __bf16 bf16x8 __attribute__((ext_vector_type(8)));
typedef __bf16 bf16x4 __attribute__((ext_vector_type(4)));
typedef float  f32x4  __attribute__((ext_vector_type(4)));
typedef unsigned int u32x4 __attribute__((ext_vector_type(4)));

// ---- d_ws layout (byte offsets). deg doubles as the scatter cursor. ----
#define WS_DEG      0           // N ints (histogram, then cursor)
#define WS_OFF      200192      // N+1 ints (CSR row offsets)
#define WS_CSUM     400640      // NCHUNK ints
#define WS_SRCS     401152      // E ints (src ids sorted by dst)
#define WS_HSRC     2961152     // N*C bf16 = 12.8 MB
// total 15,761,152 B (≤ proven 15.97 MB)

// XOR-swizzle for [16][128]-short LDS tiles: flip short-offset bits 3..5 with
// row&7 -> frag reads across 16 rows hit 8 distinct 16B slots (2-way = free).
__device__ __forceinline__ int swzS(int row, int soff) {
    return row * 128 + (soff ^ ((row & 7) << 3));
}
// [16][256]-short variant (node-update staging)
__device__ __forceinline__ int swz8(int row, int soff) {
    return row * 256 + (soff ^ ((row & 7) << 3));
}

// ---------------------------------------------------------------------------
// CSR build chain
// ---------------------------------------------------------------------------
__global__ void hist_kernel(const int* __restrict__ eidx, int* __restrict__ deg) {
    const int e = blockIdx.x * 256 + threadIdx.x;
    if (e < N_EDGES) atomicAdd(&deg[eidx[N_EDGES + e]], 1);
}

__global__ void chunksum_kernel(const int* __restrict__ deg, int* __restrict__ csum) {
    __shared__ int lds[SCAN_CHUNK];
    const int t = threadIdx.x, g = blockIdx.x * SCAN_CHUNK + t;
    lds[t] = (g < N_NODES) ? deg[g] : 0;
    __syncthreads();
    for (int s = SCAN_CHUNK / 2; s > 0; s >>= 1) {
        if (t < s) lds[t] += lds[t + s];
        __syncthreads();
    }
    if (t == 0) csum[blockIdx.x] = lds[0];
}

// writes off[] (+ off[N]) and resets deg[] to the exclusive prefix (cursor).
// Block-level offset computed in-block from csum (NCHUNK=49 < 64 lanes).
__global__ void scan_kernel(const int* __restrict__ csum, int* __restrict__ deg,
                            int* __restrict__ off) {
    __shared__ int lds[SCAN_CHUNK];
    __shared__ int scoff;
    const int t = threadIdx.x, g = blockIdx.x * SCAN_CHUNK + t;
    if (t < 64) {
        int v = (t < blockIdx.x) ? csum[t] : 0;
        #pragma unroll
        for (int s = 1; s < 64; s <<= 1) v += __shfl_xor(v, s);
        if (t == 0) scoff = v;
    }
    const int x = (g < N_NODES) ? deg[g] : 0;
    lds[t] = x;
    __syncthreads();
    for (int s = 1; s < SCAN_CHUNK; s <<= 1) {       // Hillis-Steele inclusive
        const int v = (t >= s) ? lds[t - s] : 0;
        __syncthreads();
        lds[t] += v;
        __syncthreads();
    }
    const int excl = lds[t] - x + scoff;
    if (g < N_NODES) { off[g] = excl; deg[g] = excl; }
    if (g == N_NODES - 1) off[N_NODES] = lds[t] + scoff;   // == E
}

__global__ void scatter_kernel(const int* __restrict__ eidx, int* __restrict__ cursor,
                               int* __restrict__ srcS) {
    const int e = blockIdx.x * 256 + threadIdx.x;
    if (e < N_EDGES) {
        const int r = eidx[e], c = eidx[N_EDGES + e];
        const int p = atomicAdd(&cursor[c], 1);
        srcS[p] = r;
    }
}

// ---------------------------------------------------------------------------
// Precompute Hsrc = embed @ Wmsg[0:128]          (bf16, ws)
//            Hdst = embed @ Wmsg[128:256] + b    (f32, -> d_out)
// ---------------------------------------------------------------------------
__global__ __launch_bounds__(512) void precomp_kernel(
    const float* __restrict__ embed, const float* __restrict__ Wmsg,
    const float* __restrict__ bmsg,  __bf16* __restrict__ Hsrc,
    float* __restrict__ Hdst)
{
    __shared__ short lds[16 * 128];

    const int t = threadIdx.x, lane = t & 63, wave = t >> 6;
    const int chbase = wave * 16, q = lane >> 4, nr = lane & 15;
    const int ch = chbase + nr;

    bf16x8 aS[4], aD[4];
    #pragma unroll
    for (int ks = 0; ks < 4; ++ks)
        #pragma unroll
        for (int i = 0; i < 8; ++i) {
            const int k = ks * 32 + q * 8 + i;
            aS[ks][i] = (__bf16)Wmsg[k * C + ch];
            aD[ks][i] = (__bf16)Wmsg[(128 + k) * C + ch];
        }
    float bias[4];
    #pragma unroll
    for (int r = 0; r < 4; ++r) bias[r] = bmsg[chbase + q * 4 + r];

    for (int nt = blockIdx.x; nt < NTILES; nt += gridDim.x) {
        const int n0 = nt * 16;
        {   // stage 16 nodes x 128 feats: f32 -> bf16 LDS
            const int row = t >> 5, seg = t & 31;
            const float4 f = *(const float4*)(embed + (long)(n0 + row) * C + seg * 4);
            bf16x4 v;
            v[0]=(__bf16)f.x; v[1]=(__bf16)f.y; v[2]=(__bf16)f.z; v[3]=(__bf16)f.w;
            *(bf16x4*)(&lds[swzS(row, seg * 4)]) = v;
        }
        __syncthreads();

        f32x4 hs = {0.f,0.f,0.f,0.f}, hd = {0.f,0.f,0.f,0.f};
        #pragma unroll
        for (int ks = 0; ks < 4; ++ks) {
            const bf16x8 b = *(const bf16x8*)(&lds[swzS(nr, ks * 32 + q * 8)]);
            hs = __builtin_amdgcn_mfma_f32_16x16x32_bf16(aS[ks], b, hs, 0, 0, 0);
            hd = __builtin_amdgcn_mfma_f32_16x16x32_bf16(aD[ks], b, hd, 0, 0, 0);
        }
        __syncthreads();

        const int node = n0 + nr;            // D: col=node, row(q*4+r)=ch
        bf16x4 vs;
        f32x4  vd;
        #pragma unroll
        for (int r = 0; r < 4; ++r) { vs[r] = (__bf16)hs[r]; vd[r] = hd[r] + bias[r]; }
        *(bf16x4*)(Hsrc + (long)node * C + chbase + q * 4) = vs;
        *(f32x4*)(Hdst + (long)node * C + chbase + q * 4) = vd;
    }
}

// ---------------------------------------------------------------------------
// Aggregate v2: one node per wave, 4 edges in flight (4 groups x 16 lanes,
// 8 ch/lane). No LDS, no barriers, no atomics. Hdst lives in `out`;
// overwritten by aggr after a cross-group shfl reduction.
// ---------------------------------------------------------------------------
__global__ __launch_bounds__(256) void aggr_kernel(
    const __bf16* __restrict__ Hsrc, const float* __restrict__ pos,
    const float*  __restrict__ Wmsg, const int* __restrict__ off,
    const int*    __restrict__ srcS, float* __restrict__ out)
{
    const int lane = threadIdx.x & 63;
    const int wv   = threadIdx.x >> 6;
    const int g    = lane >> 4;          // edge sub-group 0..3
    const int c8   = (lane & 15) * 8;    // channel base (8 ch/lane)

    float w2[8], hd[8], acc[8];
    *(f32x4*)&w2[0] = *(const f32x4*)(Wmsg + 256 * C + c8);
    *(f32x4*)&w2[4] = *(const f32x4*)(Wmsg + 256 * C + c8 + 4);

    const int gw = blockIdx.x * 4 + wv;
    const int nw = gridDim.x * 4;
    for (int n = gw; n < N_NODES; n += nw) {
        const int o0 = off[n], o1 = off[n + 1];
        *(f32x4*)&hd[0] = *(const f32x4*)(out + (long)n * C + c8);
        *(f32x4*)&hd[4] = *(const f32x4*)(out + (long)n * C + c8 + 4);
        const float px = pos[n * 3], py = pos[n * 3 + 1], pz = pos[n * 3 + 2];
        #pragma unroll
        for (int j = 0; j < 8; ++j) acc[j] = 0.f;

        if (o1 > o0) {
            int s = srcS[min(o0 + g, o1 - 1)];
            for (int e = o0; e < o1; e += 4) {
                // issue gathers for current edge, prefetch next src id
                const float qx = pos[s * 3], qy = pos[s * 3 + 1], qz = pos[s * 3 + 2];
                const u32x4 hu = *(const u32x4*)(Hsrc + (long)s * C + c8);
                const int sn = srcS[min(e + 4 + g, o1 - 1)];
                const float dx = qx - px, dy = qy - py, dz = qz - pz;
                const float d  = dx * dx + dy * dy + dz * dz;
                const bool valid = (e + g) < o1;
                #pragma unroll
                for (int k = 0; k < 4; ++k) {
                    const float flo = __uint_as_float(hu[k] << 16);
                    const float fhi = __uint_as_float(hu[k] & 0xffff0000u);
                    const float v0 = fmaxf(flo + hd[2*k]   + d * w2[2*k],   0.f);
                    const float v1 = fmaxf(fhi + hd[2*k+1] + d * w2[2*k+1], 0.f);
                    acc[2*k]   += valid ? v0 : 0.f;
                    acc[2*k+1] += valid ? v1 : 0.f;
                }
                s = sn;
            }
        }
        #pragma unroll
        for (int j = 0; j < 8; ++j) {        // combine the 4 edge groups
            acc[j] += __shfl_xor(acc[j], 16);
            acc[j] += __shfl_xor(acc[j], 32);
        }
        if (lane < 16) {
            *(f32x4*)(out + (long)n * C + c8)     = *(const f32x4*)&acc[0];
            *(f32x4*)(out + (long)n * C + c8 + 4) = *(const f32x4*)&acc[4];
        }
    }
}

// ---------------------------------------------------------------------------
// Node update: out = embed @ W_res + relu([embed, aggr] @ W_upd + b_upd)
// (aggr lives in `out` on entry; overwritten in place, single-owner tiles)
// ---------------------------------------------------------------------------
__global__ __launch_bounds__(512) void node_upd_kernel(
    const float* __restrict__ embed, const float* __restrict__ Wres,
    const float* __restrict__ Wupd,  const float* __restrict__ bupd,
    float* __restrict__ out)
{
    __shared__ short ldsF[16 * 256];

    const int t = threadIdx.x, lane = t & 63, wave = t >> 6;
    const int chbase = wave * 16, q = lane >> 4, nr = lane & 15;

    bf16x8 aU[8], aR[4];
    {
        const int ch = chbase + nr;
        #pragma unroll
        for (int ks = 0; ks < 8; ++ks)
            #pragma unroll
            for (int i = 0; i < 8; ++i)
                aU[ks][i] = (__bf16)Wupd[(ks*32 + q*8 + i) * C + ch];
        #pragma unroll
        for (int ks = 0; ks < 4; ++ks)
            #pragma unroll
            for (int i = 0; i < 8; ++i)
                aR[ks][i] = (__bf16)Wres[(ks*32 + q*8 + i) * C + ch];
    }
    float bu[4];
    #pragma unroll
    for (int r = 0; r < 4; ++r) bu[r] = bupd[chbase + q*4 + r];

    for (int nt = blockIdx.x; nt < NTILES; nt += gridDim.x) {
        const int n0 = nt * 16;
        {   // stage [embed(f32->bf16) | aggr(f32 in out)] for 16 nodes
            const int nn = t >> 5, seg = t & 31;
            const float* base = (seg < 16) ? embed : out;
            const float* src  = base + (long)(n0 + nn) * C + (seg & 15) * 8;
            const float4 f0 = *(const float4*)src;
            const float4 f1 = *(const float4*)(src + 4);
            bf16x8 v;
            v[0]=(__bf16)f0.x; v[1]=(__bf16)f0.y; v[2]=(__bf16)f0.z; v[3]=(__bf16)f0.w;
            v[4]=(__bf16)f1.x; v[5]=(__bf16)f1.y; v[6]=(__bf16)f1.z; v[7]=(__bf16)f1.w;
            *(bf16x8*)(&ldsF[swz8(nn, seg * 8)]) = v;
        }
        __syncthreads();

        f32x4 au = {0.f,0.f,0.f,0.f}, ar = {0.f,0.f,0.f,0.f};
        #pragma unroll
        for (int ks = 0; ks < 8; ++ks) {
            const bf16x8 b = *(const bf16x8*)(&ldsF[swz8(nr, ks * 32 + q * 8)]);
            au = __builtin_amdgcn_mfma_f32_16x16x32_bf16(aU[ks], b, au, 0, 0, 0);
        }
        #pragma unroll
        for (int ks = 0; ks < 4; ++ks) {
            const bf16x8 b = *(const bf16x8*)(&ldsF[swz8(nr, ks * 32 + q * 8)]);
            ar = __builtin_amdgcn_mfma_f32_16x16x32_bf16(aR[ks], b, ar, 0, 0, 0);
        }
        __syncthreads();

        const int node = n0 + nr;
        float* dst = out + (long)node * C + chbase + q * 4;
        #pragma unroll
        for (int r = 0; r < 4; ++r)
            dst[r] = ar[r] + fmaxf(au[r] + bu[r], 0.f);
    }
}

extern "C" void kernel_launch(void* const* d_in, const int* in_sizes, int n_in,
                              void* d_out, int out_size, void* d_ws, size_t ws_size,
                              hipStream_t stream) {
    const float* embed = (const float*)d_in[0];
    const float* pos   = (const float*)d_in[1];
    const float* Wres  = (const float*)d_in[2];
    const float* Wmsg  = (const float*)d_in[3];
    const float* bmsg  = (const float*)d_in[4];
    const float* Wupd  = (const float*)d_in[5];
    const float* bupd  = (const float*)d_in[6];
    const int*   eidx  = (const int*)d_in[7];
    float* out = (float*)d_out;

    char* ws = (char*)d_ws;
    int*    deg  = (int*)(ws + WS_DEG);     // histogram -> cursor
    int*    off  = (int*)(ws + WS_OFF);
    int*    csum = (int*)(ws + WS_CSUM);
    int*    srcS = (int*)(ws + WS_SRCS);
    __bf16* Hsrc = (__bf16*)(ws + WS_HSRC);

    hipMemsetAsync(deg, 0, N_NODES * sizeof(int), stream);
    precomp_kernel<<<1024, 512, 0, stream>>>(embed, Wmsg, bmsg, Hsrc, out);
    hist_kernel<<<N_EDGES / 256, 256, 0, stream>>>(eidx, deg);
    chunksum_kernel<<<NCHUNK, SCAN_CHUNK, 0, stream>>>(deg, csum);
    scan_kernel<<<NCHUNK, SCAN_CHUNK, 0, stream>>>(csum, deg, off);
    scatter_kernel<<<N_EDGES / 256, 256, 0, stream>>>(eidx, deg, srcS);
    aggr_kernel<<<4096, 256, 0, stream>>>(Hsrc, pos, Wmsg, off, srcS, out);
    node_upd_kernel<<<1024, 512, 0, stream>>>(embed, Wres, Wupd, bupd, out);
}

// Round 5
// 128.810 us; speedup vs baseline: 8.8108x; 1.1868x over previous
//
#include <hip/hip_runtime.h>
#include <hip/hip_bf16.h>

#define N_NODES 50000
#define N_EDGES 640000
#define C 128            // IN_C == HID
#define NB 196           // dst buckets of 256 nodes (50000 <= 196*256)
#define NTILES (N_NODES / 16)                               // 3125

typedef __bf16 bf16x8 __attribute__((ext_vector_type(8)));
typedef __bf16 bf16x4 __attribute__((ext_vector_type(4)));
typedef float  f32x4  __attribute__((ext_vector_type(4)));
typedef unsigned int u32x4 __attribute__((ext_vector_type(4)));

// ---- d_ws layout (byte offsets) ----
#define WS_BCNT  0          // NB ints (bucket histogram)
#define WS_BOFF  1024       // NB+1 ints (bucket offsets)
#define WS_GCUR  2048       // NB ints (partition cursors)
#define WS_OFF   3072       // N+1 ints (CSR row offsets)
#define WS_SRCS  203776     // E ints (src ids grouped by dst)
#define WS_HSRC  2764800    // N*C bf16 = 12.8 MB; rec[E] (4B ea) ALIASES the
                            // first 2.56 MB (dead before precomp writes Hsrc)
// total 15,564,800 B (< proven 15.97 MB)

// XOR-swizzle for [16][128]-short LDS tiles: flip short-offset bits 3..5 with
// row&7 -> frag reads across 16 rows hit 8 distinct 16B slots (2-way = free).
__device__ __forceinline__ int swzS(int row, int soff) {
    return row * 128 + (soff ^ ((row & 7) << 3));
}
// [16][256]-short variant (node-update staging)
__device__ __forceinline__ int swz8(int row, int soff) {
    return row * 256 + (soff ^ ((row & 7) << 3));
}

// ---------------------------------------------------------------------------
// CSR build, bucket-sorted: bcount -> bscan -> partition -> bucket_csr
// ---------------------------------------------------------------------------
__global__ __launch_bounds__(256) void bcount_kernel(
    const int* __restrict__ eidx, int* __restrict__ bcnt)
{
    __shared__ int h[NB];
    const int t = threadIdx.x;
    if (t < NB) h[t] = 0;
    __syncthreads();
    const int e0 = blockIdx.x * 1024;
    #pragma unroll
    for (int k = 0; k < 4; ++k)
        atomicAdd(&h[eidx[N_EDGES + e0 + k * 256 + t] >> 8], 1);
    __syncthreads();
    if (t < NB) atomicAdd(&bcnt[t], h[t]);
}

__global__ __launch_bounds__(256) void bscan_kernel(
    const int* __restrict__ bcnt, int* __restrict__ boff,
    int* __restrict__ gcur, int* __restrict__ off)
{
    __shared__ int lds[256];
    const int t = threadIdx.x;
    const int v = (t < NB) ? bcnt[t] : 0;
    lds[t] = v;
    __syncthreads();
    for (int s = 1; s < 256; s <<= 1) {
        const int u = (t >= s) ? lds[t - s] : 0;
        __syncthreads();
        lds[t] += u;
        __syncthreads();
    }
    const int excl = lds[t] - v;
    if (t < NB) { boff[t] = excl; gcur[t] = excl; }
    if (t == 0) { boff[NB] = N_EDGES; off[N_NODES] = N_EDGES; }
}

// bin 1024 edges/block by dst>>8 via LDS cursors; reserve per-bucket ranges
// with one global atomic per bucket per block; write packed 4B records
// (src | dstLocal<<16) in within-bucket contiguous runs.
__global__ __launch_bounds__(256) void partition_kernel(
    const int* __restrict__ eidx, int* __restrict__ gcur,
    unsigned* __restrict__ rec)
{
    __shared__ int cnt[NB];
    __shared__ int base[NB];
    const int t = threadIdx.x;
    if (t < NB) cnt[t] = 0;
    __syncthreads();
    const int e0 = blockIdx.x * 1024;
    int lrank[4], bb[4];
    unsigned prec[4];
    #pragma unroll
    for (int k = 0; k < 4; ++k) {
        const int e = e0 + k * 256 + t;
        const int r = eidx[e], c = eidx[N_EDGES + e];
        bb[k]   = c >> 8;
        prec[k] = (unsigned)r | ((unsigned)(c & 255) << 16);
        lrank[k] = atomicAdd(&cnt[bb[k]], 1);
    }
    __syncthreads();
    if (t < NB) base[t] = atomicAdd(&gcur[t], cnt[t]);
    __syncthreads();
    #pragma unroll
    for (int k = 0; k < 4; ++k)
        rec[base[bb[k]] + lrank[k]] = prec[k];
}

// one block per bucket: LDS deg-count over 256 nodes -> scan -> off[],
// then LDS-cursor scatter of src ids into the bucket's contiguous srcS range.
__global__ __launch_bounds__(256) void bucket_csr_kernel(
    const unsigned* __restrict__ rec, const int* __restrict__ boff,
    int* __restrict__ off, int* __restrict__ srcS)
{
    __shared__ int deg[256];
    __shared__ int cur[256];
    __shared__ int lds[256];
    const int t = threadIdx.x, b = blockIdx.x;
    const int r0 = boff[b], r1 = boff[b + 1], n0 = b << 8;
    deg[t] = 0;
    __syncthreads();
    for (int i = r0 + t; i < r1; i += 256)
        atomicAdd(&deg[rec[i] >> 16], 1);
    __syncthreads();
    const int v = deg[t];
    lds[t] = v;
    __syncthreads();
    for (int s = 1; s < 256; s <<= 1) {
        const int u = (t >= s) ? lds[t - s] : 0;
        __syncthreads();
        lds[t] += u;
        __syncthreads();
    }
    const int excl = r0 + lds[t] - v;
    cur[t] = excl;
    if (n0 + t < N_NODES) off[n0 + t] = excl;
    __syncthreads();
    for (int i = r0 + t; i < r1; i += 256) {
        const unsigned rc = rec[i];
        const int p = atomicAdd(&cur[rc >> 16], 1);
        srcS[p] = (int)(rc & 0xFFFFu);
    }
}

// ---------------------------------------------------------------------------
// Precompute Hsrc = embed @ Wmsg[0:128]          (bf16, ws)
//            Hdst = embed @ Wmsg[128:256] + b    (f32, -> d_out)
// ---------------------------------------------------------------------------
__global__ __launch_bounds__(512) void precomp_kernel(
    const float* __restrict__ embed, const float* __restrict__ Wmsg,
    const float* __restrict__ bmsg,  __bf16* __restrict__ Hsrc,
    float* __restrict__ Hdst)
{
    __shared__ short lds[16 * 128];

    const int t = threadIdx.x, lane = t & 63, wave = t >> 6;
    const int chbase = wave * 16, q = lane >> 4, nr = lane & 15;
    const int ch = chbase + nr;

    bf16x8 aS[4], aD[4];
    #pragma unroll
    for (int ks = 0; ks < 4; ++ks)
        #pragma unroll
        for (int i = 0; i < 8; ++i) {
            const int k = ks * 32 + q * 8 + i;
            aS[ks][i] = (__bf16)Wmsg[k * C + ch];
            aD[ks][i] = (__bf16)Wmsg[(128 + k) * C + ch];
        }
    float bias[4];
    #pragma unroll
    for (int r = 0; r < 4; ++r) bias[r] = bmsg[chbase + q * 4 + r];

    for (int nt = blockIdx.x; nt < NTILES; nt += gridDim.x) {
        const int n0 = nt * 16;
        {   // stage 16 nodes x 128 feats: f32 -> bf16 LDS
            const int row = t >> 5, seg = t & 31;
            const float4 f = *(const float4*)(embed + (long)(n0 + row) * C + seg * 4);
            bf16x4 v;
            v[0]=(__bf16)f.x; v[1]=(__bf16)f.y; v[2]=(__bf16)f.z; v[3]=(__bf16)f.w;
            *(bf16x4*)(&lds[swzS(row, seg * 4)]) = v;
        }
        __syncthreads();

        f32x4 hs = {0.f,0.f,0.f,0.f}, hd = {0.f,0.f,0.f,0.f};
        #pragma unroll
        for (int ks = 0; ks < 4; ++ks) {
            const bf16x8 b = *(const bf16x8*)(&lds[swzS(nr, ks * 32 + q * 8)]);
            hs = __builtin_amdgcn_mfma_f32_16x16x32_bf16(aS[ks], b, hs, 0, 0, 0);
            hd = __builtin_amdgcn_mfma_f32_16x16x32_bf16(aD[ks], b, hd, 0, 0, 0);
        }
        __syncthreads();

        const int node = n0 + nr;            // D: col=node, row(q*4+r)=ch
        bf16x4 vs;
        f32x4  vd;
        #pragma unroll
        for (int r = 0; r < 4; ++r) { vs[r] = (__bf16)hs[r]; vd[r] = hd[r] + bias[r]; }
        *(bf16x4*)(Hsrc + (long)node * C + chbase + q * 4) = vs;
        *(f32x4*)(Hdst + (long)node * C + chbase + q * 4) = vd;
    }
}

// ---------------------------------------------------------------------------
// Aggregate: one node per wave, 4 edges in flight (4 groups x 16 lanes,
// 8 ch/lane). No LDS, no barriers, no atomics. Hdst lives in `out`;
// overwritten by aggr after a cross-group shfl reduction.
// ---------------------------------------------------------------------------
__global__ __launch_bounds__(256) void aggr_kernel(
    const __bf16* __restrict__ Hsrc, const float* __restrict__ pos,
    const float*  __restrict__ Wmsg, const int* __restrict__ off,
    const int*    __restrict__ srcS, float* __restrict__ out)
{
    const int lane = threadIdx.x & 63;
    const int wv   = threadIdx.x >> 6;
    const int g    = lane >> 4;          // edge sub-group 0..3
    const int c8   = (lane & 15) * 8;    // channel base (8 ch/lane)

    float w2[8], hd[8], acc[8];
    *(f32x4*)&w2[0] = *(const f32x4*)(Wmsg + 256 * C + c8);
    *(f32x4*)&w2[4] = *(const f32x4*)(Wmsg + 256 * C + c8 + 4);

    const int gw = blockIdx.x * 4 + wv;
    const int nw = gridDim.x * 4;
    for (int n = gw; n < N_NODES; n += nw) {
        const int o0 = off[n], o1 = off[n + 1];
        *(f32x4*)&hd[0] = *(const f32x4*)(out + (long)n * C + c8);
        *(f32x4*)&hd[4] = *(const f32x4*)(out + (long)n * C + c8 + 4);
        const float px = pos[n * 3], py = pos[n * 3 + 1], pz = pos[n * 3 + 2];
        #pragma unroll
        for (int j = 0; j < 8; ++j) acc[j] = 0.f;

        if (o1 > o0) {
            int s = srcS[min(o0 + g, o1 - 1)];
            for (int e = o0; e < o1; e += 4) {
                // issue gathers for current edge, prefetch next src id
                const float qx = pos[s * 3], qy = pos[s * 3 + 1], qz = pos[s * 3 + 2];
                const u32x4 hu = *(const u32x4*)(Hsrc + (long)s * C + c8);
                const int sn = srcS[min(e + 4 + g, o1 - 1)];
                const float dx = qx - px, dy = qy - py, dz = qz - pz;
                const float d  = dx * dx + dy * dy + dz * dz;
                const bool valid = (e + g) < o1;
                #pragma unroll
                for (int k = 0; k < 4; ++k) {
                    const float flo = __uint_as_float(hu[k] << 16);
                    const float fhi = __uint_as_float(hu[k] & 0xffff0000u);
                    const float v0 = fmaxf(flo + hd[2*k]   + d * w2[2*k],   0.f);
                    const float v1 = fmaxf(fhi + hd[2*k+1] + d * w2[2*k+1], 0.f);
                    acc[2*k]   += valid ? v0 : 0.f;
                    acc[2*k+1] += valid ? v1 : 0.f;
                }
                s = sn;
            }
        }
        #pragma unroll
        for (int j = 0; j < 8; ++j) {        // combine the 4 edge groups
            acc[j] += __shfl_xor(acc[j], 16);
            acc[j] += __shfl_xor(acc[j], 32);
        }
        if (lane < 16) {
            *(f32x4*)(out + (long)n * C + c8)     = *(const f32x4*)&acc[0];
            *(f32x4*)(out + (long)n * C + c8 + 4) = *(const f32x4*)&acc[4];
        }
    }
}

// ---------------------------------------------------------------------------
// Node update: out = embed @ W_res + relu([embed, aggr] @ W_upd + b_upd)
// (aggr lives in `out` on entry; overwritten in place, single-owner tiles)
// ---------------------------------------------------------------------------
__global__ __launch_bounds__(512) void node_upd_kernel(
    const float* __restrict__ embed, const float* __restrict__ Wres,
    const float* __restrict__ Wupd,  const float* __restrict__ bupd,
    float* __restrict__ out)
{
    __shared__ short ldsF[16 * 256];

    const int t = threadIdx.x, lane = t & 63, wave = t >> 6;
    const int chbase = wave * 16, q = lane >> 4, nr = lane & 15;

    bf16x8 aU[8], aR[4];
    {
        const int ch = chbase + nr;
        #pragma unroll
        for (int ks = 0; ks < 8; ++ks)
            #pragma unroll
            for (int i = 0; i < 8; ++i)
                aU[ks][i] = (__bf16)Wupd[(ks*32 + q*8 + i) * C + ch];
        #pragma unroll
        for (int ks = 0; ks < 4; ++ks)
            #pragma unroll
            for (int i = 0; i < 8; ++i)
                aR[ks][i] = (__bf16)Wres[(ks*32 + q*8 + i) * C + ch];
    }
    float bu[4];
    #pragma unroll
    for (int r = 0; r < 4; ++r) bu[r] = bupd[chbase + q*4 + r];

    for (int nt = blockIdx.x; nt < NTILES; nt += gridDim.x) {
        const int n0 = nt * 16;
        {   // stage [embed(f32->bf16) | aggr(f32 in out)] for 16 nodes
            const int nn = t >> 5, seg = t & 31;
            const float* base = (seg < 16) ? embed : out;
            const float* src  = base + (long)(n0 + nn) * C + (seg & 15) * 8;
            const float4 f0 = *(const float4*)src;
            const float4 f1 = *(const float4*)(src + 4);
            bf16x8 v;
            v[0]=(__bf16)f0.x; v[1]=(__bf16)f0.y; v[2]=(__bf16)f0.z; v[3]=(__bf16)f0.w;
            v[4]=(__bf16)f1.x; v[5]=(__bf16)f1.y; v[6]=(__bf16)f1.z; v[7]=(__bf16)f1.w;
            *(bf16x8*)(&ldsF[swz8(nn, seg * 8)]) = v;
        }
        __syncthreads();

        f32x4 au = {0.f,0.f,0.f,0.f}, ar = {0.f,0.f,0.f,0.f};
        #pragma unroll
        for (int ks = 0; ks < 8; ++ks) {
            const bf16x8 b = *(const bf16x8*)(&ldsF[swz8(nr, ks * 32 + q * 8)]);
            au = __builtin_amdgcn_mfma_f32_16x16x32_bf16(aU[ks], b, au, 0, 0, 0);
        }
        #pragma unroll
        for (int ks = 0; ks < 4; ++ks) {
            const bf16x8 b = *(const bf16x8*)(&ldsF[swz8(nr, ks * 32 + q * 8)]);
            ar = __builtin_amdgcn_mfma_f32_16x16x32_bf16(aR[ks], b, ar, 0, 0, 0);
        }
        __syncthreads();

        const int node = n0 + nr;
        float* dst = out + (long)node * C + chbase + q * 4;
        #pragma unroll
        for (int r = 0; r < 4; ++r)
            dst[r] = ar[r] + fmaxf(au[r] + bu[r], 0.f);
    }
}

extern "C" void kernel_launch(void* const* d_in, const int* in_sizes, int n_in,
                              void* d_out, int out_size, void* d_ws, size_t ws_size,
                              hipStream_t stream) {
    const float* embed = (const float*)d_in[0];
    const float* pos   = (const float*)d_in[1];
    const float* Wres  = (const float*)d_in[2];
    const float* Wmsg  = (const float*)d_in[3];
    const float* bmsg  = (const float*)d_in[4];
    const float* Wupd  = (const float*)d_in[5];
    const float* bupd  = (const float*)d_in[6];
    const int*   eidx  = (const int*)d_in[7];
    float* out = (float*)d_out;

    char* ws = (char*)d_ws;
    int*      bcnt = (int*)(ws + WS_BCNT);
    int*      boff = (int*)(ws + WS_BOFF);
    int*      gcur = (int*)(ws + WS_GCUR);
    int*      off  = (int*)(ws + WS_OFF);
    int*      srcS = (int*)(ws + WS_SRCS);
    unsigned* rec  = (unsigned*)(ws + WS_HSRC);   // aliases Hsrc (dead by then)
    __bf16*   Hsrc = (__bf16*)(ws + WS_HSRC);

    hipMemsetAsync(bcnt, 0, NB * sizeof(int), stream);
    bcount_kernel<<<N_EDGES / 1024, 256, 0, stream>>>(eidx, bcnt);
    bscan_kernel<<<1, 256, 0, stream>>>(bcnt, boff, gcur, off);
    partition_kernel<<<N_EDGES / 1024, 256, 0, stream>>>(eidx, gcur, rec);
    bucket_csr_kernel<<<NB, 256, 0, stream>>>(rec, boff, off, srcS);
    precomp_kernel<<<1024, 512, 0, stream>>>(embed, Wmsg, bmsg, Hsrc, out);
    aggr_kernel<<<4096, 256, 0, stream>>>(Hsrc, pos, Wmsg, off, srcS, out);
    node_upd_kernel<<<1024, 512, 0, stream>>>(embed, Wres, Wupd, bupd, out);
}